// Round 4
// baseline (3520.124 us; speedup 1.0000x reference)
//
#include <hip/hip_runtime.h>
#include <math.h>

// LSTM: L=7 layers, H=49, B=1024, T=512, I=7, O=7. fp32 in/out.
//
// Round 4: latency removal around the per-step barrier.
//  - R3 measured 2530 cy/step; issue work only ~450 cy. The gap = vmcnt(0)
//    drain at __syncthreads (per-step global x load ~900cy + h store).
//  - This version: (1) raw `s_waitcnt lgkmcnt(0); s_barrier` (no vmcnt drain),
//    (2) x/h globals blocked 8 steps through LDS stage buffers (loads issued
//    6 steps before use; stores fire-and-forget, drained at kernel end),
//    (3) ONE barrier per step: A planes double-buffered by parity; EW is
//    wave-local (a wave's N-tiles contain all 4 gates of its cells), via a
//    per-wave preT slice (write b128 -> in-wave read, in-order LDS, no bar),
//    (4) bias pre-added via MFMA C-init.
//  - k-layout: [h(0..48) | pad(49..51) | x(52..52+DIN)] so h writes (j quads)
//    and x writes (k quads) are aligned b64/b16 packs in fragment order.
//  - Fragment order addr2B(m,k) = (k>>5)*512 + ((k>>3)&3)*128 + m*8 + (k&7).
//  - fp32 fidelity: A,B split to bf16 hi/lo; D += AhBh + AlBh + AhBl.

constexpr int TT = 512;
constexpr int BB = 1024;
constexpr int HH = 49;
constexpr int GG = 196;

typedef __attribute__((ext_vector_type(8))) short short8;
typedef __attribute__((ext_vector_type(4))) short short4v;
typedef __attribute__((ext_vector_type(4))) float f32x4;

__device__ __forceinline__ void bf16split(float x, short& hi, short& lo) {
    unsigned u = __float_as_uint(x);
    unsigned r = u + 0x7FFFu + ((u >> 16) & 1u);
    hi = (short)(r >> 16);
    float fhi = __uint_as_float(r & 0xFFFF0000u);
    float rem = x - fhi;
    unsigned u2 = __float_as_uint(rem);
    unsigned r2 = u2 + 0x7FFFu + ((u2 >> 16) & 1u);
    lo = (short)(r2 >> 16);
}

__device__ __forceinline__ int addr2B(int m, int k) {
    return (k >> 5) * 512 + ((k >> 3) & 3) * 128 + m * 8 + (k & 7);
}

__device__ __forceinline__ float fast_sigmoid(float x) {
    return __builtin_amdgcn_rcpf(1.0f + __expf(-x));
}
__device__ __forceinline__ float fast_tanh(float x) {
    return 1.0f - 2.0f * __builtin_amdgcn_rcpf(1.0f + __expf(2.0f * x));
}

// Workgroup barrier WITHOUT the compiler's vmcnt(0) drain: LDS ordering only.
#define WGBAR() asm volatile("s_waitcnt lgkmcnt(0)\n\ts_barrier" ::: "memory")

template<int DIN>
__global__ __launch_bounds__(448)
void lstm_fused(const float* xin,               // [B,T,DIN] (may alias hout)
                float* hout,                    // [B,T,49]
                const float* __restrict__ Wih,  // [196,DIN]
                const float* __restrict__ Whh,  // [196,49]
                const float* __restrict__ bih,  // [196]
                const float* __restrict__ bhh)  // [196]
{
    constexpr int XO      = 52;                 // x offset in k-space
    constexpr int KTOT    = XO + DIN;           // 59 or 101
    constexpr int KSTEPS  = (KTOT + 31) / 32;   // 2 or 4
    constexpr int ASIZE   = KSTEPS * 512;       // shorts per plane per parity
    constexpr int XQ      = (DIN + 3) / 4;      // x k-quads per sample
    constexpr int XC      = 4 * XQ;             // xstage padded cols
    constexpr int NS      = 4 * XQ;             // per-step stager slots
    constexpr int NLOAD   = 4 * 8 * DIN;        // elems per x block
    constexpr int NFLUSH  = 4 * 8 * HH;         // elems per h block

    __shared__ short Ahi[2][ASIZE];             // [parity][frag order]
    __shared__ short Alo[2][ASIZE];
    __shared__ float preT[13 * 64];             // per-tile [16 n'][4 m]
    __shared__ float xstage[2][4][8][XC];       // [blk parity][m][tb][col]
    __shared__ float hstage[2][4][8][52];       // [blk parity][m][tb][j]

    const int tid  = threadIdx.x;
    const int wave = tid >> 6;
    const int lane = tid & 63;
    const int quad = lane >> 4;
    const int lrow = lane & 15;
    const int b0   = blockIdx.x * 4;

    const int ntiles = (wave < 6) ? 2 : 1;
    const int tileA  = (wave < 6) ? wave : 12;
    const int tileB  = wave + 6;                // valid only if ntiles==2

    // ---- B fragments (hi/lo) + bias, pinned in VGPRs ---------------------
    short8 BH[2][KSTEPS], BL[2][KSTEPS];
    float  biasv[2];
    #pragma unroll
    for (int ti = 0; ti < 2; ++ti) {
        const int  nt    = ti ? tileB : tileA;
        const bool valid = (ti < ntiles);
        const int  np    = nt * 16 + lrow;      // permuted row r' = 4j+g
        const int  j     = np >> 2;
        const int  g     = np & 3;
        biasv[ti] = (valid && j < HH) ? (bih[g * HH + j] + bhh[g * HH + j]) : 0.0f;
        #pragma unroll
        for (int ks = 0; ks < KSTEPS; ++ks) {
            #pragma unroll
            for (int jj = 0; jj < 8; ++jj) {
                const int k = ks * 32 + quad * 8 + jj;
                float wv = 0.0f;
                if (valid && j < HH) {
                    const int r = g * HH + j;   // original row in (i,f,g,o)
                    if (k < HH)                      wv = Whh[r * HH + k];
                    else if (k >= XO && k < KTOT)    wv = Wih[r * DIN + (k - XO)];
                }
                short h_, l_;
                bf16split(wv, h_, l_);
                BH[ti][ks][jj] = h_;
                BL[ti][ks][jj] = l_;
            }
        }
    }

    // ---- EW role: lanes 0..31, one cell (j,m) per lane -------------------
    const int  ec     = lane & 15;
    const int  ew_jj  = ec >> 2;
    const int  ew_m   = ec & 3;
    const int  ew_ti  = lane >> 4;                   // 0 or 1
    const bool is_ew  = (lane < 32) && (ew_ti < ntiles);
    const int  ew_nt  = ew_ti ? tileB : tileA;
    const int  ew_j   = 4 * ew_nt + ew_jj;
    const bool ew_ok  = is_ew && (ew_j < HH);
    const int  pa0 = (ew_nt * 16 + 4 * ew_jj + 0) * 4 + ew_m;
    const int  pa1 = (ew_nt * 16 + 4 * ew_jj + 1) * 4 + ew_m;
    const int  pa2 = (ew_nt * 16 + 4 * ew_jj + 2) * 4 + ew_m;
    const int  pa3 = (ew_nt * 16 + 4 * ew_jj + 3) * 4 + ew_m;
    const int  ew_ah = addr2B(ew_m, ew_j);
    float cc = 0.0f;

    // ---- stager role: lanes 32..39, spread over waves --------------------
    const bool st_lane = (lane >= 32) && (lane < 40);
    const int  st_s    = (lane - 32) * 7 + wave;
    const bool st_on   = st_lane && (st_s < NS);
    const int  st_m    = st_on ? (st_s / XQ) : 0;
    const int  st_kq   = st_on ? (st_s % XQ) : 0;
    const int  st_ah   = addr2B(st_m, XO + 4 * st_kq);   // 4 shorts, 8B aligned

    auto stage_x = [&](int tn) {
        if (st_on && tn < TT) {
            const float4 xv = *(const float4*)&xstage[(tn >> 3) & 1][st_m][tn & 7][4 * st_kq];
            short h0, l0, h1, l1, h2, l2, h3, l3;
            bf16split(xv.x, h0, l0);
            bf16split(xv.y, h1, l1);
            bf16split(xv.z, h2, l2);
            bf16split(xv.w, h3, l3);
            short4v vh = {h0, h1, h2, h3};
            short4v vl = {l0, l1, l2, l3};
            *(short4v*)&Ahi[tn & 1][st_ah] = vh;
            *(short4v*)&Alo[tn & 1][st_ah] = vl;
        }
    };

    // ---- init: zero A planes (h0=0, pads stay 0) and xstage --------------
    for (int i = tid; i < 2 * ASIZE / 2; i += 448) {   // write as dwords
        ((unsigned*)Ahi)[i] = 0u;
        ((unsigned*)Alo)[i] = 0u;
    }
    for (int i = tid; i < 2 * 4 * 8 * XC; i += 448)
        (&xstage[0][0][0][0])[i] = 0.0f;

    // pre-load x block 0
    float xreg[4];
    #pragma unroll
    for (int jj = 0; jj < 4; ++jj) {
        const int i = tid + jj * 448;
        if (i < NLOAD) {
            const int m  = i / (8 * DIN);
            const int r  = i - m * (8 * DIN);
            const int tt = r / DIN;
            const int c  = r - tt * DIN;
            xreg[jj] = xin[((size_t)(b0 + m) * TT + tt) * DIN + c];
        }
    }
    __syncthreads();
    #pragma unroll
    for (int jj = 0; jj < 4; ++jj) {
        const int i = tid + jj * 448;
        if (i < NLOAD) {
            const int m  = i / (8 * DIN);
            const int r  = i - m * (8 * DIN);
            const int tt = r / DIN;
            const int c  = r - tt * DIN;
            xstage[0][m][tt][c] = xreg[jj];
        }
    }
    __syncthreads();
    stage_x(0);                 // x_0 -> A[0]
    __syncthreads();

    // ---- scan ------------------------------------------------------------
    for (int t = 0; t < TT; ++t) {
        const int p  = t & 1;
        const int tb = t & 7;

        // A fragments for this step (conflict-free b128 reads)
        short8 AH[KSTEPS], AL[KSTEPS];
        #pragma unroll
        for (int ks = 0; ks < KSTEPS; ++ks) {
            AH[ks] = *(const short8*)&Ahi[p][ks * 512 + lane * 8];
            AL[ks] = *(const short8*)&Alo[p][ks * 512 + lane * 8];
        }

        // chore: issue next x-block loads (float until xstage write at tb==6)
        if (tb == 0) {
            const int t0n = (t & ~7) + 8;
            if (t0n < TT) {
                #pragma unroll
                for (int jj = 0; jj < 4; ++jj) {
                    const int i = tid + jj * 448;
                    if (i < NLOAD) {
                        const int m  = i / (8 * DIN);
                        const int r  = i - m * (8 * DIN);
                        const int tt = r / DIN;
                        const int c  = r - tt * DIN;
                        xreg[jj] = xin[((size_t)(b0 + m) * TT + t0n + tt) * DIN + c];
                    }
                }
            }
        }

        // MFMA: 2 tiles, bias in C-init; preT write is wave-local
        #pragma unroll
        for (int ti = 0; ti < 2; ++ti) {
            f32x4 C = {biasv[ti], biasv[ti], biasv[ti], biasv[ti]};
            #pragma unroll
            for (int ks = 0; ks < KSTEPS; ++ks) {
                C = __builtin_amdgcn_mfma_f32_16x16x32_bf16(AH[ks], BH[ti][ks], C, 0, 0, 0);
                C = __builtin_amdgcn_mfma_f32_16x16x32_bf16(AL[ks], BH[ti][ks], C, 0, 0, 0);
                C = __builtin_amdgcn_mfma_f32_16x16x32_bf16(AH[ks], BL[ti][ks], C, 0, 0, 0);
            }
            if (ti < ntiles && lane < 16) {
                const int nt = ti ? tileB : tileA;
                *(f32x4*)&preT[(nt * 16 + lrow) * 4] = C;   // rows m=0..3
            }
        }

        // EW (wave-local: reads only this wave's preT slices)
        if (is_ew) {
            const float g0 = preT[pa0];
            const float g1 = preT[pa1];
            const float g2 = preT[pa2];
            const float g3 = preT[pa3];
            const float i_ = fast_sigmoid(g0);
            const float f_ = fast_sigmoid(g1);
            const float gg = fast_tanh(g2);
            const float o_ = fast_sigmoid(g3);
            cc = f_ * cc + i_ * gg;
            const float hv = o_ * fast_tanh(cc);
            if (ew_ok) {
                short hh, hl;
                bf16split(hv, hh, hl);
                Ahi[p ^ 1][ew_ah] = hh;
                Alo[p ^ 1][ew_ah] = hl;
                hstage[(t >> 3) & 1][ew_m][tb][ew_j] = hv;
            }
        }

        // stage x_{t+1} into A[p^1]
        stage_x(t + 1);

        // chore: write next x-block into its xstage parity buffer
        if (tb == 6) {
            const int t0n = (t & ~7) + 8;
            if (t0n < TT) {
                const int par = (t0n >> 3) & 1;
                #pragma unroll
                for (int jj = 0; jj < 4; ++jj) {
                    const int i = tid + jj * 448;
                    if (i < NLOAD) {
                        const int m  = i / (8 * DIN);
                        const int r  = i - m * (8 * DIN);
                        const int tt = r / DIN;
                        const int c  = r - tt * DIN;
                        xstage[par][m][tt][c] = xreg[jj];
                    }
                }
            }
        }

        // chore: flush previous h block to global (fire-and-forget stores)
        if (tb == 1 && t > 8) {
            const int t0p = (t & ~7) - 8;
            const int par = (t0p >> 3) & 1;
            #pragma unroll
            for (int jj = 0; jj < 4; ++jj) {
                const int i = tid + jj * 448;
                if (i < NFLUSH) {
                    const int m  = i / (8 * HH);
                    const int r  = i - m * (8 * HH);
                    const int tt = r / HH;
                    const int c  = r - tt * HH;
                    hout[((size_t)(b0 + m) * TT + t0p + tt) * HH + c] =
                        hstage[par][m][tt][c];
                }
            }
        }

        WGBAR();   // lgkm-only barrier: A[p^1], xstage, hstage visible
    }

    // flush final h block
    {
        const int t0p = TT - 8;
        const int par = (t0p >> 3) & 1;
        #pragma unroll
        for (int jj = 0; jj < 4; ++jj) {
            const int i = tid + jj * 448;
            if (i < NFLUSH) {
                const int m  = i / (8 * HH);
                const int r  = i - m * (8 * HH);
                const int tt = r / HH;
                const int c  = r - tt * HH;
                hout[((size_t)(b0 + m) * TT + t0p + tt) * HH + c] =
                    hstage[par][m][tt][c];
            }
        }
    }
}

__global__ __launch_bounds__(256)
void fc_kernel(const float* __restrict__ hbuf,  // [B,T,49]
               const float* __restrict__ fcw,   // [7,49]
               const float* __restrict__ fcb,   // [7]
               float* __restrict__ outp)        // [B,T,7]
{
    constexpr int HP = 52;
    __shared__ float w[7][HP];
    __shared__ float bsh[8];
    const int tid = threadIdx.x;
    for (int i = tid; i < 7 * HP; i += 256) {
        const int o = i / HP, k = i - o * HP;
        w[o][k] = (k < HH) ? fcw[o * HH + k] : 0.0f;
    }
    if (tid < 7) bsh[tid] = fcb[tid];
    __syncthreads();

    const size_t i = (size_t)blockIdx.x * 256 + tid;   // flat (b*T + t)
    float acc[7];
    #pragma unroll
    for (int j = 0; j < 7; ++j) acc[j] = bsh[j];
    const float* hp = hbuf + i * HH;
    #pragma unroll
    for (int k = 0; k < HH; ++k) {
        const float hv = hp[k];
        #pragma unroll
        for (int j = 0; j < 7; ++j) acc[j] = fmaf(hv, w[j][k], acc[j]);
    }
    #pragma unroll
    for (int j = 0; j < 7; ++j) outp[i * 7 + j] = acc[j];
}

extern "C" void kernel_launch(void* const* d_in, const int* in_sizes, int n_in,
                              void* d_out, int out_size, void* d_ws, size_t ws_size,
                              hipStream_t stream)
{
    const float* x    = (const float*)d_in[0];   // [B,T,7]
    const float* Wih0 = (const float*)d_in[1];   // [196,7]
    const float* Wihr = (const float*)d_in[2];   // [6,196,49]
    const float* Whh  = (const float*)d_in[3];   // [7,196,49]
    const float* bih  = (const float*)d_in[4];   // [7,196]
    const float* bhh  = (const float*)d_in[5];   // [7,196]
    const float* fcw  = (const float*)d_in[6];   // [7,49]
    const float* fcb  = (const float*)d_in[7];   // [7]
    float* outp = (float*)d_out;                 // [B,T,7]
    float* hbuf = (float*)d_ws;                  // [B,T,49] fp32 = 102.8 MB

    lstm_fused<7><<<BB / 4, 448, 0, stream>>>(x, hbuf, Wih0, Whh, bih, bhh);
    for (int l = 1; l < 7; ++l) {
        lstm_fused<49><<<BB / 4, 448, 0, stream>>>(
            hbuf, hbuf,
            Wihr + (size_t)(l - 1) * GG * HH,
            Whh  + (size_t)l * GG * HH,
            bih  + (size_t)l * GG,
            bhh  + (size_t)l * GG);
    }
    fc_kernel<<<(BB * TT) / 256, 256, 0, stream>>>(hbuf, fcw, fcb, outp);
}

// Round 5
// 3345.065 us; speedup vs baseline: 1.0523x; 1.0523x over previous
//
#include <hip/hip_runtime.h>
#include <math.h>

// LSTM: L=7, H=49, B=1024, T=512, I=7, O=7. fp32 in/out.
//
// Round 5: cross-layer pipelined persistent kernel.
//  - R4 post-mortem: step is latency-bound (2550 cy, all pipes <35%); M=4
//    wastes 3/4 of MFMA rows; per-layer serialization leaves nothing resident
//    to hide latency. Fix: M=16 samples/WG (64 WG/layer) and run ALL 7 layers
//    concurrently in one 448-WG kernel (2 WGs/CU), layers linked by ring
//    buffers in d_ws + agent-scope release/acquire flags (8-step blocks).
//  - Ring block = [8 steps][52 cols] fp32 = 1664 B = 13 HBM lines, line
//    aligned, read exactly once after its flag -> no stale-line hazard.
//    Producer: per-step fire-and-forget stores; vmcnt(0) drain at tb==2,
//    release-store flag at tb==3 (block k published at step 8(k+1)+3).
//    Consumer polls at tb==6 for block (t+2)>>3, then all-thread acquire
//    fence. Full-size rings (no wraparound) -> producers never wait ->
//    no deadlock under in-order dispatch (producer WG id < consumer WG id).
//  - MFMA 16x16x32 bf16, 3-pass hi/lo split (proven R3/R4): D rows 0..15 =
//    samples 0..15. 13 N-tiles of 16 gate-interleaved rows (r' = 4j+gate),
//    wave w owns tiles {w, w+6} (wave6: {12}). Bias via MFMA C-init.
//  - EW wave-local: preT[tile][row s][20] (padded); cell (j,s) reads its 4
//    gates as one b128; c-state in regs; h -> A[p^1] planes + ring store.
//  - A planes double-buffered by parity; x staged per-step from prefetch
//    regs (issued 2 steps ahead); lgkm-only barrier (WGBAR) per step.

constexpr int TT = 512;
constexpr int BB = 1024;
constexpr int HH = 49;
constexpr int GG = 196;

// ring: [7][1024 samples][64 blocks][8][52] fp32
constexpr size_t R_SAMP   = 64ull * 416;          // floats per sample
constexpr size_t R_LAYER  = 1024ull * R_SAMP;     // floats per layer
constexpr size_t RING_FLOATS = 7ull * R_LAYER;
constexpr size_t FLAG_INTS   = 7ull * 64 * 32;    // padded: 1 flag per 128B
constexpr size_t WS_NEEDED   = RING_FLOATS * 4 + FLAG_INTS * 4;

typedef __attribute__((ext_vector_type(8))) short short8;
typedef __attribute__((ext_vector_type(4))) short short4v;
typedef __attribute__((ext_vector_type(4))) float f32x4;

__device__ __forceinline__ float sigmoidf_(float x) {
    return 1.0f / (1.0f + __expf(-x));
}
__device__ __forceinline__ float tanhf_(float x) {
    return 1.0f - 2.0f / (1.0f + __expf(2.0f * x));
}

__device__ __forceinline__ void bf16split(float x, short& hi, short& lo) {
    unsigned u = __float_as_uint(x);
    unsigned r = u + 0x7FFFu + ((u >> 16) & 1u);
    hi = (short)(r >> 16);
    float fhi = __uint_as_float(r & 0xFFFF0000u);
    float rem = x - fhi;
    unsigned u2 = __float_as_uint(rem);
    unsigned r2 = u2 + 0x7FFFu + ((u2 >> 16) & 1u);
    lo = (short)(r2 >> 16);
}

// fragment-order element address (2B units) of A[m][k], m<16, k<128
__device__ __forceinline__ int addr2B(int m, int k) {
    return (k >> 5) * 512 + ((k >> 3) & 3) * 128 + m * 8 + (k & 7);
}

#define WGBAR() asm volatile("s_waitcnt lgkmcnt(0)\n\ts_barrier" ::: "memory")
#define VMDRAIN() asm volatile("s_waitcnt vmcnt(0)" ::: "memory")

__global__ void zero_flags(int* f, int n) {
    int i = blockIdx.x * 256 + threadIdx.x;
    if (i < n) f[i] = 0;
}

__global__ __launch_bounds__(448, 4)
void lstm_pipe(const float* __restrict__ xin,    // [B,T,7]
               float* __restrict__ ring,         // [7][1024][64][8][52]
               int* __restrict__ flags,          // [7][64][32]
               const float* __restrict__ Wih0,   // [196,7]
               const float* __restrict__ Wihr,   // [6,196,49]
               const float* __restrict__ Whh,    // [7,196,49]
               const float* __restrict__ bih,    // [7,196]
               const float* __restrict__ bhh)    // [7,196]
{
    __shared__ short Ahi[2][2048];               // [parity][frag order]
    __shared__ short Alo[2][2048];
    __shared__ float preT[13 * 16 * 20];         // [tile][row s][20 pad]

    const int tid  = threadIdx.x;
    const int wave = tid >> 6;
    const int lane = tid & 63;
    const int quad = lane >> 4;
    const int lrow = lane & 15;

    const int l   = blockIdx.x >> 6;             // layer 0..6
    const int grp = blockIdx.x & 63;             // sample group
    const int b0  = grp << 4;                    // 16 samples

    const int DIN  = (l == 0) ? 7 : 49;
    const int KSRT = (l == 0) ? 2 : 4;           // active k-steps
    const float* Wih = (l == 0) ? Wih0 : (Wihr + (size_t)(l - 1) * GG * HH);
    const float* Whl = Whh + (size_t)l * GG * HH;
    const float* bi  = bih + (size_t)l * GG;
    const float* bh  = bhh + (size_t)l * GG;

    const float* rin  = ring + (size_t)(l - 1) * R_LAYER;
    float*       rout = ring + (size_t)l * R_LAYER;
    int* flag_in  = flags + (size_t)(l - 1) * 64 * 32 + (size_t)grp * 32;
    int* flag_out = flags + (size_t)l * 64 * 32 + (size_t)grp * 32;

    const int ntiles = (wave < 6) ? 2 : 1;
    const int tA = (wave < 6) ? wave : 12;
    const int tB = wave + 6;                     // valid if wave<6

    // ---- B fragments (hi/lo) + bias in VGPRs -----------------------------
    short8 BH[2][4], BL[2][4];
    float  biasv[2];
    #pragma unroll
    for (int ti = 0; ti < 2; ++ti) {
        const int  nt    = ti ? tB : tA;
        const bool valid = (ti < ntiles) && (nt < 13);
        const int  np    = nt * 16 + lrow;       // permuted row r' = 4j+g
        const int  j     = np >> 2;
        const int  g     = np & 3;
        const bool jb    = valid && (j < HH);
        biasv[ti] = jb ? (bi[g * HH + j] + bh[g * HH + j]) : 0.0f;
        #pragma unroll
        for (int ks = 0; ks < 4; ++ks) {
            #pragma unroll
            for (int jj = 0; jj < 8; ++jj) {
                const int k = ks * 32 + quad * 8 + jj;
                float wv = 0.0f;
                if (jb) {
                    const int r = g * HH + j;
                    if (k < HH)                       wv = Whl[r * HH + k];
                    else if (k >= 52 && k < 52 + DIN) wv = Wih[r * DIN + (k - 52)];
                }
                short h_, l_;
                bf16split(wv, h_, l_);
                BH[ti][ks][jj] = h_;
                BL[ti][ks][jj] = l_;
            }
        }
    }

    // ---- EW cells: lane owns (tile, j = 4*nt+quad, sample s = lrow) ------
    const int  j0 = 4 * tA + quad;
    const int  j1 = 4 * tB + quad;
    const bool v0 = (j0 < HH);                   // tA<=12 always
    const bool v1 = (wave < 6);                  // then j1<=47<49
    const int  ah0 = addr2B(lrow, j0);
    const int  ah1 = addr2B(lrow, j1);
    float* rc0 = rout + (size_t)(b0 + lrow) * R_SAMP + j0;
    float* rc1 = rout + (size_t)(b0 + lrow) * R_SAMP + j1;
    float cc0 = 0.0f, cc1 = 0.0f;

    // ---- loader role -----------------------------------------------------
    bool is_ld;
    int  ld_m, ld_kx, a_st;
    const float* gb;                             // per-lane load base
    if (l == 0) {
        is_ld = (tid < 112);                     // 16 samples x 7 cols
        ld_m  = tid / 7;
        ld_kx = tid - ld_m * 7;
        a_st  = addr2B(ld_m & 15, 52 + ld_kx);
        gb    = xin + ((size_t)(b0 + (ld_m & 15)) * TT) * 7 + ld_kx;
    } else {
        is_ld = (tid < 208);                     // 16 samples x 13 quads
        ld_m  = tid / 13;
        ld_kx = tid - ld_m * 13;                 // k-quad
        a_st  = addr2B(ld_m & 15, 52 + 4 * ld_kx);
        gb    = rin + (size_t)(b0 + (ld_m & 15)) * R_SAMP + 4 * ld_kx;
    }

    // ---- init ------------------------------------------------------------
    for (int i = tid; i < 2048; i += 448) {
        ((unsigned*)Ahi)[i] = 0u;
        ((unsigned*)Alo)[i] = 0u;
    }
    __syncthreads();

    if (l > 0) {                                 // wait for block 0
        if (tid == 0) {
            while (__hip_atomic_load(flag_in, __ATOMIC_ACQUIRE,
                                     __HIP_MEMORY_SCOPE_AGENT) < 1)
                __builtin_amdgcn_s_sleep(8);
        }
        __syncthreads();
        __builtin_amdgcn_fence(__ATOMIC_ACQUIRE, "agent");
    }

    float4 xr0 = {0, 0, 0, 0}, xr1 = {0, 0, 0, 0};
    if (is_ld) {
        if (l == 0) { xr0.x = gb[0]; xr1.x = gb[7]; }
        else        { xr0 = *(const float4*)gb; xr1 = *(const float4*)(gb + 468); }
        // 468 = off(t'=1) = 0*416 + 1*52 ... wait off(1) = 52. fixed below.
    }
    // NOTE: for l>0 the t'=1 offset is 52 (same block 0), recompute correctly:
    if (is_ld && l > 0) xr1 = *(const float4*)(gb + 52);

    // stage x_0 -> A[0]
    if (is_ld) {
        if (l == 0) {
            short h_, l_;
            bf16split(xr0.x, h_, l_);
            Ahi[0][a_st] = h_; Alo[0][a_st] = l_;
        } else {
            short h0,l0_,h1,l1_,h2,l2_,h3,l3_;
            bf16split(xr0.x,h0,l0_); bf16split(xr0.y,h1,l1_);
            bf16split(xr0.z,h2,l2_); bf16split(xr0.w,h3,l3_);
            short4v vh = {h0,h1,h2,h3}, vl = {l0_,l1_,l2_,l3_};
            *(short4v*)&Ahi[0][a_st] = vh;
            *(short4v*)&Alo[0][a_st] = vl;
        }
    }
    __syncthreads();

    // ---- scan ------------------------------------------------------------
    for (int t = 0; t < TT; ++t) {
        const int p  = t & 1;
        const int tb = t & 7;

        // producer chores (layers 0..5)
        if (l < 6 && tb == 2) VMDRAIN();         // block (t>>3)-1 stores done
        if (l < 6 && tb == 3 && (t >> 3) >= 1 && tid == 0)
            __hip_atomic_store(flag_out, t >> 3, __ATOMIC_RELEASE,
                               __HIP_MEMORY_SCOPE_AGENT);

        // consumer gate before loads cross into a new block
        if (l > 0 && tb == 6 && (t + 2) < TT) {
            const int want = ((t + 2) >> 3) + 1;
            if (tid == 0) {
                while (__hip_atomic_load(flag_in, __ATOMIC_ACQUIRE,
                                         __HIP_MEMORY_SCOPE_AGENT) < want)
                    __builtin_amdgcn_s_sleep(8);
            }
            WGBAR();
            __builtin_amdgcn_fence(__ATOMIC_ACQUIRE, "agent");
        }

        // issue prefetch load for t+2
        float4 xnew = {0, 0, 0, 0};
        const bool ldnow = is_ld && (t + 2) < TT;
        if (ldnow) {
            if (l == 0) xnew.x = gb[(size_t)(t + 2) * 7];
            else {
                const int offn = ((t + 2) >> 3) * 416 + ((t + 2) & 7) * 52;
                xnew = *(const float4*)(gb + offn);
            }
        }

        // A fragments (parity p), conflict-free b128
        short8 AH[4], AL[4];
        #pragma unroll
        for (int ks = 0; ks < 4; ++ks) {
            if (ks < KSRT) {
                AH[ks] = *(const short8*)&Ahi[p][ks * 512 + lane * 8];
                AL[ks] = *(const short8*)&Alo[p][ks * 512 + lane * 8];
            }
        }

        // MFMA: tile A (all waves) + tile B (waves 0..5)
        f32x4 C0 = {biasv[0], biasv[0], biasv[0], biasv[0]};
        #pragma unroll
        for (int ks = 0; ks < 4; ++ks) {
            if (ks < KSRT) {
                C0 = __builtin_amdgcn_mfma_f32_16x16x32_bf16(AH[ks], BH[0][ks], C0, 0, 0, 0);
                C0 = __builtin_amdgcn_mfma_f32_16x16x32_bf16(AL[ks], BH[0][ks], C0, 0, 0, 0);
                C0 = __builtin_amdgcn_mfma_f32_16x16x32_bf16(AH[ks], BL[0][ks], C0, 0, 0, 0);
            }
        }
        #pragma unroll
        for (int r = 0; r < 4; ++r)
            preT[(tA * 16 + 4 * quad + r) * 20 + lrow] = C0[r];

        if (wave < 6) {
            f32x4 C1 = {biasv[1], biasv[1], biasv[1], biasv[1]};
            #pragma unroll
            for (int ks = 0; ks < 4; ++ks) {
                if (ks < KSRT) {
                    C1 = __builtin_amdgcn_mfma_f32_16x16x32_bf16(AH[ks], BH[1][ks], C1, 0, 0, 0);
                    C1 = __builtin_amdgcn_mfma_f32_16x16x32_bf16(AL[ks], BH[1][ks], C1, 0, 0, 0);
                    C1 = __builtin_amdgcn_mfma_f32_16x16x32_bf16(AH[ks], BL[1][ks], C1, 0, 0, 0);
                }
            }
            #pragma unroll
            for (int r = 0; r < 4; ++r)
                preT[(tB * 16 + 4 * quad + r) * 20 + lrow] = C1[r];
        }

        // EW (wave-local preT read-after-write; lgkm ordering in-wave)
        const int offc = (t >> 3) * 416 + tb * 52;   // uniform ring offset
        if (v0) {
            const f32x4 gt = *(const f32x4*)&preT[(tA * 16 + lrow) * 20 + 4 * quad];
            const float i_ = sigmoidf_(gt.x);
            const float f_ = sigmoidf_(gt.y);
            const float g_ = tanhf_(gt.z);
            const float o_ = sigmoidf_(gt.w);
            cc0 = f_ * cc0 + i_ * g_;
            const float hv = o_ * tanhf_(cc0);
            short hh, hl;
            bf16split(hv, hh, hl);
            Ahi[p ^ 1][ah0] = hh;
            Alo[p ^ 1][ah0] = hl;
            rc0[offc] = hv;
        }
        if (v1) {
            const f32x4 gt = *(const f32x4*)&preT[(tB * 16 + lrow) * 20 + 4 * quad];
            const float i_ = sigmoidf_(gt.x);
            const float f_ = sigmoidf_(gt.y);
            const float g_ = tanhf_(gt.z);
            const float o_ = sigmoidf_(gt.w);
            cc1 = f_ * cc1 + i_ * g_;
            const float hv = o_ * tanhf_(cc1);
            short hh, hl;
            bf16split(hv, hh, hl);
            Ahi[p ^ 1][ah1] = hh;
            Alo[p ^ 1][ah1] = hl;
            rc1[offc] = hv;
        }

        // stage x_{t+1} -> A[p^1] from the reg slot loaded at t-1
        if (is_ld && (t + 1) < TT) {
            const float4 xv = ((t + 1) & 1) ? xr1 : xr0;
            if (l == 0) {
                short h_, l_;
                bf16split(xv.x, h_, l_);
                Ahi[p ^ 1][a_st] = h_; Alo[p ^ 1][a_st] = l_;
            } else {
                short h0,l0_,h1,l1_,h2,l2_,h3,l3_;
                bf16split(xv.x,h0,l0_); bf16split(xv.y,h1,l1_);
                bf16split(xv.z,h2,l2_); bf16split(xv.w,h3,l3_);
                short4v vh = {h0,h1,h2,h3}, vl = {l0_,l1_,l2_,l3_};
                *(short4v*)&Ahi[p ^ 1][a_st] = vh;
                *(short4v*)&Alo[p ^ 1][a_st] = vl;
            }
        }
        if (ldnow) { if (t & 1) xr1 = xnew; else xr0 = xnew; }

        WGBAR();   // lgkm-only: A[p^1] + preT reuse safe for next step
    }

    // epilogue: publish completion
    if (l < 6) {
        VMDRAIN();
        __syncthreads();
        if (tid == 0)
            __hip_atomic_store(flag_out, 64, __ATOMIC_RELEASE,
                               __HIP_MEMORY_SCOPE_AGENT);
    }
}

__global__ __launch_bounds__(256)
void fc_ring(const float* __restrict__ ring6,   // [1024][64][8][52]
             const float* __restrict__ fcw,     // [7,49]
             const float* __restrict__ fcb,     // [7]
             float* __restrict__ outp)          // [B,T,7]
{
    constexpr int HP = 52;
    __shared__ float w[7][HP];
    __shared__ float bsh[8];
    const int tid = threadIdx.x;
    for (int i = tid; i < 7 * HP; i += 256) {
        const int o = i / HP, k = i - o * HP;
        w[o][k] = (k < HH) ? fcw[o * HH + k] : 0.0f;
    }
    if (tid < 7) bsh[tid] = fcb[tid];
    __syncthreads();

    const size_t i = (size_t)blockIdx.x * 256 + tid;   // flat b*T+t
    const int b = (int)(i >> 9);
    const int t = (int)(i & 511);
    const float* hp = ring6 + (size_t)b * R_SAMP + (t >> 3) * 416 + (t & 7) * 52;
    float acc[7];
    #pragma unroll
    for (int j = 0; j < 7; ++j) acc[j] = bsh[j];
    #pragma unroll
    for (int k = 0; k < HH; ++k) {
        const float hv = hp[k];
        #pragma unroll
        for (int j = 0; j < 7; ++j) acc[j] = fmaf(hv, w[j][k], acc[j]);
    }
    #pragma unroll
    for (int j = 0; j < 7; ++j) outp[i * 7 + j] = acc[j];
}

// ======================= fallback path (R4, per-layer) ======================

template<int DIN>
__global__ __launch_bounds__(448)
void lstm_fb(const float* xin, float* hout,
             const float* __restrict__ Wih, const float* __restrict__ Whh,
             const float* __restrict__ bihp, const float* __restrict__ bhhp)
{
    constexpr int XO = 52;
    constexpr int KTOT = XO + DIN;
    constexpr int KSTEPS = (KTOT + 31) / 32;
    __shared__ short Ahi[2][KSTEPS * 512];
    __shared__ short Alo[2][KSTEPS * 512];
    __shared__ float preT[13 * 64];

    const int tid = threadIdx.x, wave = tid >> 6, lane = tid & 63;
    const int quad = lane >> 4, lrow = lane & 15;
    const int b0 = blockIdx.x * 4;
    const int ntiles = (wave < 6) ? 2 : 1;
    const int tileA = (wave < 6) ? wave : 12;
    const int tileB = wave + 6;

    short8 BH[2][KSTEPS], BL[2][KSTEPS];
    float biasv[2];
    #pragma unroll
    for (int ti = 0; ti < 2; ++ti) {
        const int nt = ti ? tileB : tileA;
        const bool valid = (ti < ntiles);
        const int np = nt * 16 + lrow, j = np >> 2, g = np & 3;
        biasv[ti] = (valid && j < HH) ? (bihp[g*HH+j] + bhhp[g*HH+j]) : 0.0f;
        #pragma unroll
        for (int ks = 0; ks < KSTEPS; ++ks)
            #pragma unroll
            for (int jj = 0; jj < 8; ++jj) {
                const int k = ks * 32 + quad * 8 + jj;
                float wv = 0.0f;
                if (valid && j < HH) {
                    const int r = g * HH + j;
                    if (k < HH) wv = Whh[r * HH + k];
                    else if (k >= XO && k < KTOT) wv = Wih[r * DIN + (k - XO)];
                }
                short h_, l_; bf16split(wv, h_, l_);
                BH[ti][ks][jj] = h_; BL[ti][ks][jj] = l_;
            }
    }

    const int ec = lane & 15, ew_jj = ec >> 2, ew_m = ec & 3, ew_ti = lane >> 4;
    const bool is_ew = (lane < 32) && (ew_ti < ntiles);
    const int ew_nt = ew_ti ? tileB : tileA;
    const int ew_j = 4 * ew_nt + ew_jj;
    const bool ew_ok = is_ew && (ew_j < HH);
    const int pa0 = (ew_nt*16 + 4*ew_jj + 0)*4 + ew_m;
    const int pa1 = (ew_nt*16 + 4*ew_jj + 1)*4 + ew_m;
    const int pa2 = (ew_nt*16 + 4*ew_jj + 2)*4 + ew_m;
    const int pa3 = (ew_nt*16 + 4*ew_jj + 3)*4 + ew_m;
    const int ew_ah = addr2B(ew_m, ew_j);
    float cc = 0.0f;

    const int lx = tid;
    const bool is_loader = (lx < 4 * DIN);
    const int ld_m = is_loader ? (lx & 3) : 0, ld_k = is_loader ? (lx >> 2) : 0;
    const int xaddr = addr2B(ld_m, XO + ld_k);
    const size_t xbase = ((size_t)(b0 + ld_m) * TT) * DIN + ld_k;
    float* houtp = hout + ((size_t)(b0 + ew_m) * TT) * HH + (ew_ok ? ew_j : 0);

    for (int i = tid; i < KSTEPS * 512; i += 448) {
        ((unsigned*)Ahi)[i] = 0u; ((unsigned*)Alo)[i] = 0u;
    }
    __syncthreads();
    if (is_loader) {
        short h_, l_; bf16split(xin[xbase], h_, l_);
        Ahi[0][xaddr] = h_; Alo[0][xaddr] = l_;
    }
    __syncthreads();

    for (int t = 0; t < TT; ++t) {
        const int p = t & 1;
        float xnext = 0.0f;
        if (is_loader && (t + 1 < TT)) xnext = xin[xbase + (size_t)(t+1) * DIN];

        short8 AH[KSTEPS], AL[KSTEPS];
        #pragma unroll
        for (int ks = 0; ks < KSTEPS; ++ks) {
            AH[ks] = *(const short8*)&Ahi[p][ks * 512 + lane * 8];
            AL[ks] = *(const short8*)&Alo[p][ks * 512 + lane * 8];
        }
        #pragma unroll
        for (int ti = 0; ti < 2; ++ti) {
            f32x4 C = {biasv[ti], biasv[ti], biasv[ti], biasv[ti]};
            #pragma unroll
            for (int ks = 0; ks < KSTEPS; ++ks) {
                C = __builtin_amdgcn_mfma_f32_16x16x32_bf16(AH[ks], BH[ti][ks], C, 0, 0, 0);
                C = __builtin_amdgcn_mfma_f32_16x16x32_bf16(AL[ks], BH[ti][ks], C, 0, 0, 0);
                C = __builtin_amdgcn_mfma_f32_16x16x32_bf16(AH[ks], BL[ti][ks], C, 0, 0, 0);
            }
            if (ti < ntiles && lane < 16) {
                const int nt = ti ? tileB : tileA;
                *(f32x4*)&preT[(nt * 16 + lrow) * 4] = C;
            }
        }
        if (is_ew) {
            const float i_ = sigmoidf_(preT[pa0]);
            const float f_ = sigmoidf_(preT[pa1]);
            const float g_ = tanhf_(preT[pa2]);
            const float o_ = sigmoidf_(preT[pa3]);
            cc = f_ * cc + i_ * g_;
            const float hv = o_ * tanhf_(cc);
            if (ew_ok) {
                short hh, hl; bf16split(hv, hh, hl);
                Ahi[p ^ 1][ew_ah] = hh; Alo[p ^ 1][ew_ah] = hl;
                houtp[(size_t)t * HH] = hv;
            }
        }
        if (is_loader && (t + 1 < TT)) {
            short h_, l_; bf16split(xnext, h_, l_);
            Ahi[p ^ 1][xaddr] = h_; Alo[p ^ 1][xaddr] = l_;
        }
        __syncthreads();
    }
}

__global__ __launch_bounds__(256)
void fc_fb(const float* __restrict__ hbuf, const float* __restrict__ fcw,
           const float* __restrict__ fcb, float* __restrict__ outp)
{
    constexpr int HP = 52;
    __shared__ float w[7][HP];
    __shared__ float bsh[8];
    const int tid = threadIdx.x;
    for (int i = tid; i < 7 * HP; i += 256) {
        const int o = i / HP, k = i - o * HP;
        w[o][k] = (k < HH) ? fcw[o * HH + k] : 0.0f;
    }
    if (tid < 7) bsh[tid] = fcb[tid];
    __syncthreads();
    const size_t i = (size_t)blockIdx.x * 256 + tid;
    float acc[7];
    #pragma unroll
    for (int j = 0; j < 7; ++j) acc[j] = bsh[j];
    const float* hp = hbuf + i * HH;
    #pragma unroll
    for (int k = 0; k < HH; ++k) {
        const float hv = hp[k];
        #pragma unroll
        for (int j = 0; j < 7; ++j) acc[j] = fmaf(hv, w[j][k], acc[j]);
    }
    #pragma unroll
    for (int j = 0; j < 7; ++j) outp[i * 7 + j] = acc[j];
}

extern "C" void kernel_launch(void* const* d_in, const int* in_sizes, int n_in,
                              void* d_out, int out_size, void* d_ws, size_t ws_size,
                              hipStream_t stream)
{
    const float* x    = (const float*)d_in[0];
    const float* Wih0 = (const float*)d_in[1];
    const float* Wihr = (const float*)d_in[2];
    const float* Whh  = (const float*)d_in[3];
    const float* bih  = (const float*)d_in[4];
    const float* bhh  = (const float*)d_in[5];
    const float* fcw  = (const float*)d_in[6];
    const float* fcb  = (const float*)d_in[7];
    float* outp = (float*)d_out;

    if (ws_size >= WS_NEEDED) {
        float* ring  = (float*)d_ws;
        int*   flags = (int*)((char*)d_ws + RING_FLOATS * 4);
        zero_flags<<<(int)((FLAG_INTS + 255) / 256), 256, 0, stream>>>(
            flags, (int)FLAG_INTS);
        lstm_pipe<<<448, 448, 0, stream>>>(x, ring, flags, Wih0, Wihr,
                                           Whh, bih, bhh);
        fc_ring<<<(BB * TT) / 256, 256, 0, stream>>>(
            ring + 6ull * R_LAYER, fcw, fcb, outp);
    } else {
        float* hbuf = (float*)d_ws;   // [B,T,49]
        lstm_fb<7><<<BB / 4, 448, 0, stream>>>(x, hbuf, Wih0, Whh, bih, bhh);
        for (int l = 1; l < 7; ++l) {
            lstm_fb<49><<<BB / 4, 448, 0, stream>>>(
                hbuf, hbuf,
                Wihr + (size_t)(l - 1) * GG * HH,
                Whh  + (size_t)l * GG * HH,
                bih  + (size_t)l * GG,
                bhh  + (size_t)l * GG);
        }
        fc_fb<<<(BB * TT) / 256, 256, 0, stream>>>(hbuf, fcw, fcb, outp);
    }
}